// Round 8
// baseline (1324.586 us; speedup 1.0000x reference)
//
#include <hip/hip_runtime.h>
#include <stdint.h>

// Problem constants (match reference)
#define T_TOK 8192
#define HID   1024
#define INTER 4096
#define NE    8
#define TOPK  2
#define CAP   2048            // min(ceil(T*K*CF/E), T) = 2048
#define EC    (NE * CAP)      // 16384 slots

// Workspace layout (bytes).
//  [0,   64MB)  WgT  bf16 (E, INTER, HID)   gate_w transposed
//  [64,  128MB) WuT  bf16 (E, INTER, HID)
//  [128, 192MB) WdT  bf16 (E, HID, INTER)   down_w transposed
//  [192, 224MB) Xe   bf16 (EC, HID)         gathered tokens
//  [224, 352MB) interB bf16 (EC, INTER)     silu(g)*u
//  [352, 384MB) pout bf16 (EC, HID)         permuted expert output
//  [416MB .. )  perm int (T,2), assign int (EC)

typedef __attribute__((ext_vector_type(8))) short bf16x8;
typedef __attribute__((ext_vector_type(4))) float f32x4;

static __device__ __forceinline__ unsigned short f2bf(float f) {
    union { float f; unsigned u; } a; a.f = f;
    unsigned r = a.u + 0x7FFFu + ((a.u >> 16) & 1u);   // round-nearest-even
    return (unsigned short)(r >> 16);
}
static __device__ __forceinline__ float bf2f(unsigned short b) {
    union { unsigned u; float f; } a; a.u = ((unsigned)b) << 16;
    return a.f;
}

static __device__ __forceinline__ void gload(const unsigned short* g, unsigned short* l) {
    // async global->LDS, 16B/lane; LDS dest = wave-uniform base + lane*16
    __builtin_amdgcn_global_load_lds((__attribute__((address_space(1))) void*)(uintptr_t)g,
                                     (__attribute__((address_space(3))) void*)l, 16, 0, 0);
}

#define BAR() do { asm volatile("" ::: "memory"); __builtin_amdgcn_s_barrier(); asm volatile("" ::: "memory"); } while (0)
#define WAITVM(N) asm volatile("s_waitcnt vmcnt(" #N ")" ::: "memory")

// ---------------------------------------------------------------- routing ---
__global__ __launch_bounds__(512) void route_kernel(const int* __restrict__ eidx,
                                                    int* __restrict__ perm,
                                                    int* __restrict__ assign) {
    int tid = threadIdx.x;
    for (int i = tid; i < EC; i += 512) assign[i] = 0;   // empty slot -> token 0
    __syncthreads();
    int e = tid >> 6;          // wave index == expert
    int lane = tid & 63;
    const int TPL = T_TOK / 64;                          // 128 tokens per lane
    int t0 = lane * TPL;
    int cnt = 0;
    for (int t = t0; t < t0 + TPL; ++t) {
        int e0 = eidx[t * 2], e1 = eidx[t * 2 + 1];
        cnt += (e0 == e) + (e1 == e);
    }
    int incl = cnt;
    #pragma unroll
    for (int off = 1; off < 64; off <<= 1) {
        int n = __shfl_up(incl, off, 64);
        if (lane >= off) incl += n;
    }
    int run = incl - cnt;
    for (int t = t0; t < t0 + TPL; ++t) {
        int e0 = eidx[t * 2], e1 = eidx[t * 2 + 1];
        int c = (e0 == e) + (e1 == e);
        if (c) {
            run += c;
            int pos = run;                       // inclusive (1-based)
            bool keep = (pos <= CAP);
            int pi = keep ? (pos + e * CAP) : 0;
            if (e0 == e) perm[t * 2]     = pi;
            if (e1 == e) perm[t * 2 + 1] = pi;
            if (keep) assign[pi - 1] = t;
        }
    }
}

// --------------------------------------------------- transpose + fp32->bf16 --
__global__ __launch_bounds__(256) void transpose_cvt2(const float* __restrict__ in0,
                                                      unsigned short* __restrict__ out0,
                                                      const float* __restrict__ in1,
                                                      unsigned short* __restrict__ out1) {
    __shared__ unsigned short tile[64][68];
    int z = blockIdx.z;
    const float* in = (z < 8) ? in0 : in1;
    unsigned short* out = (z < 8) ? out0 : out1;
    int e = z & 7;
    const int R = HID, Cc = INTER;
    const float* inp = in + (size_t)e * R * Cc;
    unsigned short* outp = out + (size_t)e * R * Cc;
    int c0 = blockIdx.x * 64, r0 = blockIdx.y * 64;
    int t = threadIdx.x;
    int x = t & 15;
    int ry = t >> 4;
    #pragma unroll
    for (int j = 0; j < 4; ++j) {
        int row = ry + 16 * j;
        float4 v = *(const float4*)(inp + (size_t)(r0 + row) * Cc + c0 + 4 * x);
        ushort4 o;
        o.x = f2bf(v.x); o.y = f2bf(v.y); o.z = f2bf(v.z); o.w = f2bf(v.w);
        *(ushort4*)&tile[row][4 * x] = o;
    }
    __syncthreads();
    #pragma unroll
    for (int j = 0; j < 4; ++j) {
        int oc = ry + 16 * j;
        ushort4 o;
        o.x = tile[4 * x + 0][oc];
        o.y = tile[4 * x + 1][oc];
        o.z = tile[4 * x + 2][oc];
        o.w = tile[4 * x + 3][oc];
        *(ushort4*)(outp + (size_t)(c0 + oc) * R + r0 + 4 * x) = o;
    }
}

__global__ __launch_bounds__(256) void transpose_cvt(const float* __restrict__ in,
                                                     unsigned short* __restrict__ out,
                                                     int R, int Cc) {
    __shared__ unsigned short tile[64][68];
    int e = blockIdx.z;
    const float* inp = in + (size_t)e * R * Cc;
    unsigned short* outp = out + (size_t)e * R * Cc;
    int c0 = blockIdx.x * 64, r0 = blockIdx.y * 64;
    int t = threadIdx.x;
    int x = t & 15;
    int ry = t >> 4;
    #pragma unroll
    for (int j = 0; j < 4; ++j) {
        int row = ry + 16 * j;
        float4 v = *(const float4*)(inp + (size_t)(r0 + row) * Cc + c0 + 4 * x);
        ushort4 o;
        o.x = f2bf(v.x); o.y = f2bf(v.y); o.z = f2bf(v.z); o.w = f2bf(v.w);
        *(ushort4*)&tile[row][4 * x] = o;
    }
    __syncthreads();
    #pragma unroll
    for (int j = 0; j < 4; ++j) {
        int oc = ry + 16 * j;
        ushort4 o;
        o.x = tile[4 * x + 0][oc];
        o.y = tile[4 * x + 1][oc];
        o.z = tile[4 * x + 2][oc];
        o.w = tile[4 * x + 3][oc];
        *(ushort4*)(outp + (size_t)(c0 + oc) * R + r0 + 4 * x) = o;
    }
}

// ------------------------------------------------------- gather + cvt tokens -
__global__ __launch_bounds__(256) void gather_cvt(const float* __restrict__ hs,
                                                  const int* __restrict__ assign,
                                                  unsigned short* __restrict__ xe) {
    int s = blockIdx.x;
    int tok = assign[s];
    const float* src = hs + (size_t)tok * HID;
    unsigned short* dst = xe + (size_t)s * HID;
    int h = threadIdx.x * 4;
    float4 v = *(const float4*)(src + h);
    ushort4 o;
    o.x = f2bf(v.x); o.y = f2bf(v.y); o.z = f2bf(v.z); o.w = f2bf(v.w);
    *(ushort4*)(dst + h) = o;
}

// =============================================================================
// R7: LDS-bandwidth fix. Theory: R6 was LDS-bound (96KB LDS/CU-Ktile = 768 cyc
// vs MFMA 310 cyc -> 42% MfmaUtil). Fix: A operand global->VGPR DIRECT (16B/
// lane, 16 fully-used 64B lines per wave-load, L2/XCD-resident panels); only B
// stays in LDS (gload_lds, 3 x 8KB buffers, counted vmcnt). LDS/CU-Ktile drops
// to ~36KB (~290 cyc) ~= MFMA.
// A regs double-buffered via 2x-unrolled loop (static indexing, rule #20).
// vmcnt FIFO per iter: issue [Bst(t+2) x2, A(t+1) x8]; WAITVM(10) retires
// [Bst(t+1), A(t)]; B(t) LDS was staged 2 tiles ago. Reads of B(t) placed
// AFTER the barrier. Two barriers per tile (R6 showed barrier cost ~0).
// down grid swapped to (e, n, m): contiguous blocks share the 2MB A-panel
// (L2-fits) instead of spreading it.
// =============================================================================

// ------------------------------- fused gate+up GEMM + SiLU*mul (dual acc) ----
__global__ __launch_bounds__(256, 2) void gateup_gemm(const unsigned short* __restrict__ Xe,
                                                      const unsigned short* __restrict__ WgT,
                                                      const unsigned short* __restrict__ WuT,
                                                      unsigned short* __restrict__ interB) {
    extern __shared__ __align__(16) unsigned short smemU[];
    const int K = HID;          // 1024
    const int NT = K / 32;      // 32 K-tiles

    int e  = blockIdx.x;                 // x fastest -> XCD-pinned per expert
    int m0 = blockIdx.y * 256;
    int n0 = blockIdx.z * 64;

    int tid = threadIdx.x;
    int lane = tid & 63, w = tid >> 6;
    int lm = lane & 15, hi = lane >> 4;
    int wm = w >> 1, wn = w & 1;

    // B read offset within a 2048-elem panel (64r x 32k), swizzled
    const int swz  = (hi ^ ((lm >> 1) & 3)) << 3;
    const int bOff = (wn * 32 + lm) * 32 + swz;

    // B stage source (pre-swizzled global col); per-wave LDS dest offset
    int sr = lane >> 2;
    int sc = ((lane & 3) ^ ((lane >> 3) & 3)) << 3;
    const unsigned short* gS = WgT + ((size_t)e * INTER + n0 + w * 16 + sr) * K + sc;
    const unsigned short* uS = WuT + ((size_t)e * INTER + n0 + w * 16 + sr) * K + sc;
    const int dW = w * 512;

    // A direct global->reg: per-lane row base; frag mi at +mi*16*K, tile at +tk
    const unsigned short* aP = Xe + ((size_t)e * CAP + m0 + wm * 128 + lm) * K + hi * 8;

    f32x4 zero = {0.f, 0.f, 0.f, 0.f};
    f32x4 accG[8][2], accU[8][2];
    #pragma unroll
    for (int i = 0; i < 8; ++i) {
        accG[i][0] = zero; accG[i][1] = zero;
        accU[i][0] = zero; accU[i][1] = zero;
    }

    int bR = 0, bM = 4096, bS = 8192;   // 3 buffers x 4096 elems (G 2048 | U 2048)
    bf16x8 aC[8], aN[8];

    // prologue: issue [Bst(0) x2, Bst(1) x2, A(0) x8]; retire Bst(0)
    gload(gS,      smemU + bR + dW);  gload(uS,      smemU + bR + 2048 + dW);
    gload(gS + 32, smemU + bM + dW);  gload(uS + 32, smemU + bM + 2048 + dW);
    #pragma unroll
    for (int mi = 0; mi < 8; ++mi) aC[mi] = *(const bf16x8*)(aP + mi * 16 * K);
    WAITVM(10);
    BAR();

#define GU_TILE(AC, AN, tkc) \
    { \
        gload(gS + (tkc) + 64, smemU + bS + dW); \
        gload(uS + (tkc) + 64, smemU + bS + 2048 + dW); \
        _Pragma("unroll") \
        for (int mi = 0; mi < 8; ++mi) \
            AN[mi] = *(const bf16x8*)(aP + mi * 16 * K + (tkc) + 32); \
        WAITVM(10); \
        BAR(); \
        { \
            bf16x8 g0 = *(const bf16x8*)(smemU + bR + bOff); \
            bf16x8 g1 = *(const bf16x8*)(smemU + bR + bOff + 512); \
            bf16x8 u0 = *(const bf16x8*)(smemU + bR + 2048 + bOff); \
            bf16x8 u1 = *(const bf16x8*)(smemU + bR + 2048 + bOff + 512); \
            __builtin_amdgcn_s_setprio(1); \
            _Pragma("unroll") \
            for (int mi = 0; mi < 8; ++mi) { \
                accG[mi][0] = __builtin_amdgcn_mfma_f32_16x16x32_bf16(AC[mi], g0, accG[mi][0], 0, 0, 0); \
                accG[mi][1] = __builtin_amdgcn_mfma_f32_16x16x32_bf16(AC[mi], g1, accG[mi][1], 0, 0, 0); \
                accU[mi][0] = __builtin_amdgcn_mfma_f32_16x16x32_bf16(AC[mi], u0, accU[mi][0], 0, 0, 0); \
                accU[mi][1] = __builtin_amdgcn_mfma_f32_16x16x32_bf16(AC[mi], u1, accU[mi][1], 0, 0, 0); \
            } \
            __builtin_amdgcn_s_setprio(0); \
        } \
        BAR(); \
        int _bt = bR; bR = bM; bM = bS; bS = _bt; \
    }

    int tk = 0;
    for (int t = 0; t < NT - 2; t += 2) {   // NT-2 = 30 iterations (even)
        GU_TILE(aC, aN, tk);
        GU_TILE(aN, aC, tk + 32);
        tk += 64;
    }
    // peel NT-2: issue A(NT-1); use aC = A(NT-2)
    {
        #pragma unroll
        for (int mi = 0; mi < 8; ++mi) aN[mi] = *(const bf16x8*)(aP + mi * 16 * K + tk + 32);
        WAITVM(8);
        BAR();
        bf16x8 g0 = *(const bf16x8*)(smemU + bR + bOff);
        bf16x8 g1 = *(const bf16x8*)(smemU + bR + bOff + 512);
        bf16x8 u0 = *(const bf16x8*)(smemU + bR + 2048 + bOff);
        bf16x8 u1 = *(const bf16x8*)(smemU + bR + 2048 + bOff + 512);
        #pragma unroll
        for (int mi = 0; mi < 8; ++mi) {
            accG[mi][0] = __builtin_amdgcn_mfma_f32_16x16x32_bf16(aC[mi], g0, accG[mi][0], 0, 0, 0);
            accG[mi][1] = __builtin_amdgcn_mfma_f32_16x16x32_bf16(aC[mi], g1, accG[mi][1], 0, 0, 0);
            accU[mi][0] = __builtin_amdgcn_mfma_f32_16x16x32_bf16(aC[mi], u0, accU[mi][0], 0, 0, 0);
            accU[mi][1] = __builtin_amdgcn_mfma_f32_16x16x32_bf16(aC[mi], u1, accU[mi][1], 0, 0, 0);
        }
        BAR();
        int _bt = bR; bR = bM; bM = bS; bS = _bt;
    }
    // peel NT-1: use aN = A(NT-1)
    {
        WAITVM(0);
        bf16x8 g0 = *(const bf16x8*)(smemU + bR + bOff);
        bf16x8 g1 = *(const bf16x8*)(smemU + bR + bOff + 512);
        bf16x8 u0 = *(const bf16x8*)(smemU + bR + 2048 + bOff);
        bf16x8 u1 = *(const bf16x8*)(smemU + bR + 2048 + bOff + 512);
        #pragma unroll
        for (int mi = 0; mi < 8; ++mi) {
            accG[mi][0] = __builtin_amdgcn_mfma_f32_16x16x32_bf16(aN[mi], g0, accG[mi][0], 0, 0, 0);
            accG[mi][1] = __builtin_amdgcn_mfma_f32_16x16x32_bf16(aN[mi], g1, accG[mi][1], 0, 0, 0);
            accU[mi][0] = __builtin_amdgcn_mfma_f32_16x16x32_bf16(aN[mi], u0, accU[mi][0], 0, 0, 0);
            accU[mi][1] = __builtin_amdgcn_mfma_f32_16x16x32_bf16(aN[mi], u1, accU[mi][1], 0, 0, 0);
        }
    }
#undef GU_TILE

    // epilogue: silu(G)*U -> bounce [256][72] -> vector stores
    __syncthreads();
    unsigned short* bounce = smemU;
    #pragma unroll
    for (int mi = 0; mi < 8; ++mi)
        #pragma unroll
        for (int nf = 0; nf < 2; ++nf) {
            f32x4 g4 = accG[mi][nf], u4 = accU[mi][nf];
            #pragma unroll
            for (int r = 0; r < 4; ++r) {
                int row = wm * 128 + mi * 16 + hi * 4 + r;
                int col = wn * 32 + nf * 16 + lm;
                float g = g4[r];
                float s = g / (1.f + __expf(-g)) * u4[r];
                bounce[row * 72 + col] = f2bf(s);
            }
        }
    __syncthreads();
    {
        unsigned short* Op = interB + ((size_t)e * CAP + m0) * INTER + n0;
        int rr = tid >> 3, cc = (tid & 7) * 8;
        #pragma unroll
        for (int j = 0; j < 8; ++j) {
            int row = rr + 32 * j;
            bf16x8 v = *(const bf16x8*)&bounce[row * 72 + cc];
            *(bf16x8*)(Op + (size_t)row * INTER + cc) = v;
        }
    }
}

// ------------------------------------------------------------- down GEMM ----
__global__ __launch_bounds__(256, 2) void down_gemm(const unsigned short* __restrict__ interB,
                                                    const unsigned short* __restrict__ WdT,
                                                    unsigned short* __restrict__ pout) {
    extern __shared__ __align__(16) unsigned short smemU[];
    const int K = INTER;        // 4096
    const int NT = K / 32;      // 128 K-tiles

    int e  = blockIdx.x;
    int n0 = blockIdx.y * 128;          // y=n: contiguous blocks share A-panel
    int m0 = blockIdx.z * 256;

    int tid = threadIdx.x;
    int lane = tid & 63, w = tid >> 6;
    int lm = lane & 15, hi = lane >> 4;
    int wm = w >> 1, wn = w & 1;

    const int swz  = (hi ^ ((lm >> 1) & 3)) << 3;
    const int bOff = (wn * 32 + lm) * 32 + swz;

    int sr = lane >> 2;
    int sc = ((lane & 3) ^ ((lane >> 3) & 3)) << 3;
    int rb1 = (w >> 1) * 64 + (w & 1) * 16;       // LDS rows w*16.. hold these
    const unsigned short* b1S = WdT + ((size_t)e * HID + n0 + rb1 + sr) * K + sc;
    const unsigned short* b2S = WdT + ((size_t)e * HID + n0 + rb1 + 32 + sr) * K + sc;
    const int dW = w * 512;

    const unsigned short* aP = interB + ((size_t)e * CAP + m0 + wm * 128 + lm) * K + hi * 8;

    f32x4 zero = {0.f, 0.f, 0.f, 0.f};
    f32x4 acc[8][4];
    #pragma unroll
    for (int i = 0; i < 8; ++i)
        #pragma unroll
        for (int j = 0; j < 4; ++j) acc[i][j] = zero;

    int bR = 0, bM = 4096, bS = 8192;
    bf16x8 aC[8], aN[8];

    gload(b1S,      smemU + bR + dW);  gload(b2S,      smemU + bR + 2048 + dW);
    gload(b1S + 32, smemU + bM + dW);  gload(b2S + 32, smemU + bM + 2048 + dW);
    #pragma unroll
    for (int mi = 0; mi < 8; ++mi) aC[mi] = *(const bf16x8*)(aP + mi * 16 * K);
    WAITVM(10);
    BAR();

#define DN_TILE(AC, AN, tkc) \
    { \
        gload(b1S + (tkc) + 64, smemU + bS + dW); \
        gload(b2S + (tkc) + 64, smemU + bS + 2048 + dW); \
        _Pragma("unroll") \
        for (int mi = 0; mi < 8; ++mi) \
            AN[mi] = *(const bf16x8*)(aP + mi * 16 * K + (tkc) + 32); \
        WAITVM(10); \
        BAR(); \
        { \
            bf16x8 b0 = *(const bf16x8*)(smemU + bR + bOff); \
            bf16x8 b1 = *(const bf16x8*)(smemU + bR + bOff + 512); \
            bf16x8 b2 = *(const bf16x8*)(smemU + bR + 2048 + bOff); \
            bf16x8 b3 = *(const bf16x8*)(smemU + bR + 2048 + bOff + 512); \
            __builtin_amdgcn_s_setprio(1); \
            _Pragma("unroll") \
            for (int mi = 0; mi < 8; ++mi) { \
                acc[mi][0] = __builtin_amdgcn_mfma_f32_16x16x32_bf16(AC[mi], b0, acc[mi][0], 0, 0, 0); \
                acc[mi][1] = __builtin_amdgcn_mfma_f32_16x16x32_bf16(AC[mi], b1, acc[mi][1], 0, 0, 0); \
                acc[mi][2] = __builtin_amdgcn_mfma_f32_16x16x32_bf16(AC[mi], b2, acc[mi][2], 0, 0, 0); \
                acc[mi][3] = __builtin_amdgcn_mfma_f32_16x16x32_bf16(AC[mi], b3, acc[mi][3], 0, 0, 0); \
            } \
            __builtin_amdgcn_s_setprio(0); \
        } \
        BAR(); \
        int _bt = bR; bR = bM; bM = bS; bS = _bt; \
    }

    int tk = 0;
    for (int t = 0; t < NT - 2; t += 2) {   // 126 iterations (even)
        DN_TILE(aC, aN, tk);
        DN_TILE(aN, aC, tk + 32);
        tk += 64;
    }
    {   // peel NT-2
        #pragma unroll
        for (int mi = 0; mi < 8; ++mi) aN[mi] = *(const bf16x8*)(aP + mi * 16 * K + tk + 32);
        WAITVM(8);
        BAR();
        bf16x8 b0 = *(const bf16x8*)(smemU + bR + bOff);
        bf16x8 b1 = *(const bf16x8*)(smemU + bR + bOff + 512);
        bf16x8 b2 = *(const bf16x8*)(smemU + bR + 2048 + bOff);
        bf16x8 b3 = *(const bf16x8*)(smemU + bR + 2048 + bOff + 512);
        #pragma unroll
        for (int mi = 0; mi < 8; ++mi) {
            acc[mi][0] = __builtin_amdgcn_mfma_f32_16x16x32_bf16(aC[mi], b0, acc[mi][0], 0, 0, 0);
            acc[mi][1] = __builtin_amdgcn_mfma_f32_16x16x32_bf16(aC[mi], b1, acc[mi][1], 0, 0, 0);
            acc[mi][2] = __builtin_amdgcn_mfma_f32_16x16x32_bf16(aC[mi], b2, acc[mi][2], 0, 0, 0);
            acc[mi][3] = __builtin_amdgcn_mfma_f32_16x16x32_bf16(aC[mi], b3, acc[mi][3], 0, 0, 0);
        }
        BAR();
        int _bt = bR; bR = bM; bM = bS; bS = _bt;
    }
    {   // peel NT-1
        WAITVM(0);
        bf16x8 b0 = *(const bf16x8*)(smemU + bR + bOff);
        bf16x8 b1 = *(const bf16x8*)(smemU + bR + bOff + 512);
        bf16x8 b2 = *(const bf16x8*)(smemU + bR + 2048 + bOff);
        bf16x8 b3 = *(const bf16x8*)(smemU + bR + 2048 + bOff + 512);
        #pragma unroll
        for (int mi = 0; mi < 8; ++mi) {
            acc[mi][0] = __builtin_amdgcn_mfma_f32_16x16x32_bf16(aN[mi], b0, acc[mi][0], 0, 0, 0);
            acc[mi][1] = __builtin_amdgcn_mfma_f32_16x16x32_bf16(aN[mi], b1, acc[mi][1], 0, 0, 0);
            acc[mi][2] = __builtin_amdgcn_mfma_f32_16x16x32_bf16(aN[mi], b2, acc[mi][2], 0, 0, 0);
            acc[mi][3] = __builtin_amdgcn_mfma_f32_16x16x32_bf16(aN[mi], b3, acc[mi][3], 0, 0, 0);
        }
    }
#undef DN_TILE

    // epilogue: two bounce rounds; round R covers cols wn*64 + R*32 + [0,32)
    unsigned short* bounce = smemU;
    unsigned short* Op = pout + ((size_t)e * CAP + m0) * HID + n0;
    int rr = tid >> 3, c8 = tid & 7;
    int colp = c8 * 8;
    #pragma unroll
    for (int R = 0; R < 2; ++R) {
        __syncthreads();
        #pragma unroll
        for (int mi = 0; mi < 8; ++mi)
            #pragma unroll
            for (int nf = 0; nf < 2; ++nf) {
                f32x4 a4 = acc[mi][2 * R + nf];
                #pragma unroll
                for (int r = 0; r < 4; ++r) {
                    int row = wm * 128 + mi * 16 + hi * 4 + r;
                    int col = wn * 32 + nf * 16 + lm;   // compacted col'
                    bounce[row * 72 + col] = f2bf(a4[r]);
                }
            }
        __syncthreads();
        int gcol = (colp >> 5) * 64 + R * 32 + (colp & 31);
        #pragma unroll
        for (int j = 0; j < 8; ++j) {
            int row = rr + 32 * j;
            bf16x8 v = *(const bf16x8*)&bounce[row * 72 + colp];
            *(bf16x8*)(Op + (size_t)row * HID + gcol) = v;
        }
    }
}

// --------------------------------------------------------------- combine ----
__global__ __launch_bounds__(256) void combine_kernel(const float* __restrict__ aff,
                                                      const int* __restrict__ eidx,
                                                      const int* __restrict__ perm,
                                                      const unsigned short* __restrict__ pout,
                                                      float* __restrict__ out) {
    int t = blockIdx.x;
    int e0 = eidx[t * 2], e1 = eidx[t * 2 + 1];
    int p0 = perm[t * 2], p1 = perm[t * 2 + 1];
    bool k0 = p0 > 0, k1 = p1 > 0;
    float a0 = aff[t * NE + e0], a1 = aff[t * NE + e1];
    float denom = (k0 ? fabsf(a0) : 0.f) + ((e1 != e0 && k1) ? fabsf(a1) : 0.f);
    denom = fmaxf(denom, 1e-12f);
    float w0 = k0 ? a0 / denom : 0.f;
    float w1 = k1 ? a1 / denom : 0.f;
    int s0 = k0 ? p0 - 1 : 0;
    int s1 = k1 ? p1 - 1 : 0;
    int h = threadIdx.x * 4;
    ushort4 v0 = *(const ushort4*)(pout + (size_t)s0 * HID + h);
    ushort4 v1 = *(const ushort4*)(pout + (size_t)s1 * HID + h);
    float4 o;
    o.x = w0 * bf2f(v0.x) + w1 * bf2f(v1.x);
    o.y = w0 * bf2f(v0.y) + w1 * bf2f(v1.y);
    o.z = w0 * bf2f(v0.z) + w1 * bf2f(v1.z);
    o.w = w0 * bf2f(v0.w) + w1 * bf2f(v1.w);
    *(float4*)(out + (size_t)t * HID + h) = o;
}

// ----------------------------------------------------------------- launch ---
extern "C" void kernel_launch(void* const* d_in, const int* in_sizes, int n_in,
                              void* d_out, int out_size, void* d_ws, size_t ws_size,
                              hipStream_t stream) {
    (void)in_sizes; (void)n_in; (void)out_size; (void)ws_size;
    const float* hs   = (const float*)d_in[0];   // (T, HID)
    const float* aff  = (const float*)d_in[1];   // (T, NE)
    const float* gw   = (const float*)d_in[2];   // (NE, HID, INTER)
    const float* uw   = (const float*)d_in[3];   // (NE, HID, INTER)
    const float* dw   = (const float*)d_in[4];   // (NE, INTER, HID)
    const int*   eidx = (const int*)d_in[5];     // (T, TOPK)
    float* out = (float*)d_out;

    char* ws = (char*)d_ws;
    unsigned short* WgT    = (unsigned short*)(ws);
    unsigned short* WuT    = (unsigned short*)(ws + ((size_t)64  << 20));
    unsigned short* WdT    = (unsigned short*)(ws + ((size_t)128 << 20));
    unsigned short* Xe     = (unsigned short*)(ws + ((size_t)192 << 20));
    unsigned short* interB = (unsigned short*)(ws + ((size_t)224 << 20));
    unsigned short* pout   = (unsigned short*)(ws + ((size_t)352 << 20));
    int*            perm   = (int*)           (ws + ((size_t)416 << 20));
    int*            assign = perm + (T_TOK * TOPK);

    static int attr_set = 0;
    if (!attr_set) {
        (void)hipFuncSetAttribute((const void*)gateup_gemm,
                                  hipFuncAttributeMaxDynamicSharedMemorySize, 36864);
        (void)hipFuncSetAttribute((const void*)down_gemm,
                                  hipFuncAttributeMaxDynamicSharedMemorySize, 36864);
        attr_set = 1;
    }

    route_kernel<<<1, 512, 0, stream>>>(eidx, perm, assign);
    transpose_cvt2<<<dim3(INTER / 64, HID / 64, 16), 256, 0, stream>>>(uw, WuT, gw, WgT);
    transpose_cvt<<<dim3(HID / 64, INTER / 64, NE), 256, 0, stream>>>(dw, WdT, INTER, HID);
    gather_cvt<<<EC, 256, 0, stream>>>(hs, assign, Xe);
    gateup_gemm<<<dim3(8, 8, 64), 256, 36864, stream>>>(Xe, WgT, WuT, interB);
    down_gemm<<<dim3(8, 8, 8), 256, 36864, stream>>>(interB, WdT, pout);
    combine_kernel<<<T_TOK, 256, 0, stream>>>(aff, eidx, perm, pout, out);
}